// Round 22
// baseline (392.612 us; speedup 1.0000x reference)
//
#include <hip/hip_runtime.h>

static constexpr int NBRS = 21;
static constexpr int Nv   = 12288;
static constexpr int BV   = 4 * Nv;            // 49152 rows
static constexpr int NE   = Nv * NBRS;         // 258048 edges
static constexpr float BN_EPS = 1e-5f;

typedef __bf16 bf16x4 __attribute__((ext_vector_type(4)));
typedef __bf16 bf16x8 __attribute__((ext_vector_type(8)));
typedef float  f32x4  __attribute__((ext_vector_type(4)));

__device__ __forceinline__ int xcd_swz(int bid, int grid)
{
    return (bid & 7) * (grid >> 3) + (bid >> 3);
}

// ---------------- SPMM (C=8, fp32, float4: 2 threads/row).
// MODE 0: y = acc; MODE 2: y = acc + x0.
template<int MODE>
__global__ __launch_bounds__(256)
void spmm8_kernel(float* __restrict__ y, const float* __restrict__ x,
                  const float* __restrict__ x0,
                  const int2* __restrict__ edges)
{
    int idx = xcd_swz(blockIdx.x, gridDim.x) * 256 + threadIdx.x;   // over BV*2
    int c4 = idx & 1;
    int row = idx >> 1;
    int v = row % Nv;
    int b = row / Nv;
    int e0 = v * NBRS;
    const float4* x4 = (const float4*)x;
    float4 acc = {0.f, 0.f, 0.f, 0.f};
    #pragma unroll
    for (int j = 0; j < NBRS; ++j) {
        const int2 ed = edges[e0 + j];
        const float a = __int_as_float(ed.x);
        const int u = ed.y;
        float4 xv = x4[(size_t)(b * Nv + u) * 2 + c4];
        acc.x = fmaf(a, xv.x, acc.x);
        acc.y = fmaf(a, xv.y, acc.y);
        acc.z = fmaf(a, xv.z, acc.z);
        acc.w = fmaf(a, xv.w, acc.w);
    }
    if (MODE == 2) {
        float4 p = ((const float4*)x0)[idx];
        acc.x += p.x; acc.y += p.y; acc.z += p.z; acc.w += p.w;
    }
    ((float4*)y)[idx] = acc;
}

// ---------------- SPMM C=64, bf16x8 per thread, 8 threads/row.
// BNG: apply relu(BN(.)) computed on the fly from raw stats (s, q).
template<bool BNG>
__global__ __launch_bounds__(256)
void spmm64_kernel(__bf16* __restrict__ y, const __bf16* __restrict__ x,
                   const int2* __restrict__ edges,
                   const float* __restrict__ st, const float* __restrict__ g,
                   const float* __restrict__ be, float invN)
{
    __shared__ __align__(16) float s_a[BNG ? 64 : 4];
    __shared__ __align__(16) float s_b[BNG ? 64 : 4];
    if (BNG) {
        if (threadIdx.x < 64) {
            const int c = threadIdx.x;
            const float s = st[c], qq = st[256 + c];
            const float m = s * invN;
            const float a = g[c] * rsqrtf(qq * invN - m * m + BN_EPS);
            s_a[c] = a; s_b[c] = be[c] - m * a;
        }
        __syncthreads();
    }
    int idx = xcd_swz(blockIdx.x, gridDim.x) * 256 + threadIdx.x;   // over BV*8
    int q = idx % 8;
    int v = (idx / 8) % Nv;
    int b = idx / (8 * Nv);
    int e0 = v * NBRS;
    const bf16x8* x8 = (const bf16x8*)x;
    float4 aL, aH, bL, bH;
    if (BNG) {
        aL = *(const float4*)(s_a + q * 8);     aH = *(const float4*)(s_a + q * 8 + 4);
        bL = *(const float4*)(s_b + q * 8);     bH = *(const float4*)(s_b + q * 8 + 4);
    }
    float acc[8];
    #pragma unroll
    for (int t = 0; t < 8; ++t) acc[t] = 0.f;
    #pragma unroll
    for (int j = 0; j < NBRS; ++j) {
        const int2 ed = edges[e0 + j];
        const float a = __int_as_float(ed.x);
        const int u = ed.y;
        bf16x8 hv = x8[(size_t)(b * Nv + u) * 8 + q];
        float xv[8];
        #pragma unroll
        for (int t = 0; t < 8; ++t) xv[t] = (float)hv[t];
        if (BNG) {
            xv[0] = fmaxf(fmaf(xv[0], aL.x, bL.x), 0.f);
            xv[1] = fmaxf(fmaf(xv[1], aL.y, bL.y), 0.f);
            xv[2] = fmaxf(fmaf(xv[2], aL.z, bL.z), 0.f);
            xv[3] = fmaxf(fmaf(xv[3], aL.w, bL.w), 0.f);
            xv[4] = fmaxf(fmaf(xv[4], aH.x, bH.x), 0.f);
            xv[5] = fmaxf(fmaf(xv[5], aH.y, bH.y), 0.f);
            xv[6] = fmaxf(fmaf(xv[6], aH.z, bH.z), 0.f);
            xv[7] = fmaxf(fmaf(xv[7], aH.w, bH.w), 0.f);
        }
        #pragma unroll
        for (int t = 0; t < 8; ++t) acc[t] = fmaf(a, xv[t], acc[t]);
    }
    bf16x8 o;
    #pragma unroll
    for (int t = 0; t < 8; ++t) o[t] = (__bf16)acc[t];
    ((bf16x8*)y)[idx] = o;
}

// ---------------- unified pack: cheb-folded weights + edge list
__global__ __launch_bounds__(256)
void pack_all_kernel(const float* __restrict__ w1, const float* __restrict__ w2,
                     const float* __restrict__ c1, const float* __restrict__ c2,
                     const float* __restrict__ c3, const float* __restrict__ w3,
                     const float* __restrict__ b3,
                     const float* __restrict__ eval_, const int* __restrict__ col,
                     __bf16* __restrict__ wb, float* __restrict__ bpack,
                     int2* __restrict__ edges)
{
    int t = blockIdx.x * 256 + threadIdx.x;
    if (t >= 194560) {
        int i = t - 194560;
        if (i < 32) { bpack[i] = (i < 8) ? b3[i] : 0.f; return; }
        int e = t - 194592;
        if (e < NE) edges[e] = make_int2(__float_as_int(eval_[e]), col[e]);
        return;
    }
    const float* src; int KSRC, FOUT, FIN, local; bool fold = false, isW3 = false;
    if (t < 2048)        { src = w1;  KSRC = 24;  FOUT = 64;  FIN = 8;  local = t; fold = true; }
    else if (t < 51200)  { src = w2;  KSRC = 192; FOUT = 256; FIN = 64; local = t - 2048; fold = true; }
    else if (t < 100352) { int i = (t - 51200) / 16384;  src = c1 + (size_t)i * 16384;
                           KSRC = 256; FOUT = 64;  FIN = 256; local = (t - 51200) % 16384; }
    else if (t < 137216) { int i = (t - 100352) / 12288; src = c2 + (size_t)i * 12288;
                           KSRC = 192; FOUT = 64;  FIN = 64; local = (t - 100352) % 12288; fold = true; }
    else if (t < 186368) { int i = (t - 137216) / 16384; src = c3 + (size_t)i * 16384;
                           KSRC = 64;  FOUT = 256; FIN = 64; local = (t - 137216) % 16384; }
    else                 { src = w3;  KSRC = 256; FOUT = 32; FIN = 256; local = t - 186368; isW3 = true; }
    const int j    = local & 7;
    const int lane = (local >> 3) & 63;
    const int rest = local >> 9;
    const int NT = FOUT >> 4;
    const int nt = rest % NT;
    const int ks = rest / NT;
    const int k = ks * 32 + (lane >> 4) * 8 + j;
    const int o = nt * 16 + (lane & 15);
    float v = 0.f;
    if (isW3) {
        const int zj = o >> 3, oo = o & 7;
        if (zj == 0)      v = src[(size_t)k * 8 + oo] - src[(size_t)2 * 2048 + k * 8 + oo];
        else if (zj == 1) v = src[(size_t)2048 + k * 8 + oo];
        else if (zj == 2) v = 2.f * src[(size_t)2 * 2048 + k * 8 + oo];
    } else if (k < KSRC) {
        if (fold) {
            if (k < FIN)          v = src[(size_t)k * FOUT + o] - src[(size_t)(k + 2 * FIN) * FOUT + o];
            else if (k < 2 * FIN) v = src[(size_t)k * FOUT + o];
            else                  v = 2.f * src[(size_t)k * FOUT + o];
        } else {
            v = src[(size_t)k * FOUT + o];
        }
    }
    wb[t] = (__bf16)v;
}

// ---------------- MFMA GEMM. BN params reconstructed from raw stats (st,g,be)
// in an LDS preamble. STATS: atomically accumulate (s,q) into stats_out.
// RESID: stage = BN1(x0) + base(x1); BASEBN: base = relu(BN2(base)); WRITEBACK -> wbk.
template<int FOUT, int KFIN, int KPAD, int FIN, int NSRC,
         bool STATS, bool BN0, bool HAS_BIAS, bool PACKOUT, bool INBF, bool OUTBF,
         bool RESID = false, bool BASEBN = false, bool WRITEBACK = false>
__global__ __launch_bounds__(256)
void gemm_mfma_kernel(const void* __restrict__ x0, const void* __restrict__ x1,
                      const void* __restrict__ x2,
                      const __bf16* __restrict__ wp, const float* __restrict__ bias,
                      const float* __restrict__ st1, const float* __restrict__ g1,
                      const float* __restrict__ be1,
                      const float* __restrict__ st2, const float* __restrict__ g2,
                      const float* __restrict__ be2,
                      void* __restrict__ out, float* __restrict__ stats_out,
                      __bf16* __restrict__ wbk, float invN)
{
    constexpr int NT    = FOUT / 16;
    constexpr int NSTEP = KPAD / 32;
    constexpr bool COLS = (NT % 4 == 0);
    constexpr int NT2   = COLS ? NT / 4 : NT;
    constexpr int LDKB  = KPAD + 8;
    constexpr int LDC   = FOUT + 4;
    constexpr bool ANYBN = BN0 || RESID || BASEBN;
    constexpr size_t XS_B  = (size_t)64 * LDKB * 2;
    constexpr size_t RPK_B = COLS ? (size_t)16 * LDC * 4 : 0;
    constexpr size_t SMEM  = XS_B > RPK_B ? XS_B : RPK_B;
    __shared__ __align__(16) char smem[SMEM];
    __shared__ __align__(16) float abst[ANYBN ? 1024 : 4];
    __bf16* xs = (__bf16*)smem;
    float* ab1a = abst;        float* ab1b = abst + 256;
    float* ab2a = abst + 512;  float* ab2b = abst + 768;

    const int tid = threadIdx.x;
    const int m0 = blockIdx.x * 64;

    // ---- BN (a,b) reconstruction preamble
    if constexpr (BN0 || RESID) {
        for (int c = tid; c < FIN; c += 256) {
            const float s = st1[c], qq = st1[256 + c];
            const float m = s * invN;
            const float a = g1[c] * rsqrtf(qq * invN - m * m + BN_EPS);
            ab1a[c] = a; ab1b[c] = be1[c] - m * a;
        }
    }
    if constexpr (BASEBN) {
        for (int c = tid; c < FIN; c += 256) {
            const float s = st2[c], qq = st2[256 + c];
            const float m = s * invN;
            const float a = g2[c] * rsqrtf(qq * invN - m * m + BN_EPS);
            ab2a[c] = a; ab2b[c] = be2[c] - m * a;
        }
    }
    if constexpr (ANYBN) __syncthreads();

    constexpr int NF4 = 64 * (KPAD / 4);
    for (int f = tid; f < NF4; f += 256) {
        const int r  = f / (KPAD / 4);
        const int ki = (f % (KPAD / 4)) * 4;
        bf16x4 h;
        if (KFIN == KPAD || ki < KFIN) {
            int i; int kk;
            if constexpr (NSRC == 1) { i = ki; kk = 0; }
            else { kk = ki / FIN; i = ki % FIN; }
            if constexpr (RESID) {
                const __bf16* srcy = (const __bf16*)x0;
                const __bf16* srct = (const __bf16*)x1;
                bf16x4 hy = *(const bf16x4*)(srcy + (size_t)(m0 + r) * FIN + i);
                bf16x4 ht = *(const bf16x4*)(srct + (size_t)(m0 + r) * FIN + i);
                const float4 a4 = *(const float4*)(ab1a + i);
                const float4 b4 = *(const float4*)(ab1b + i);
                float bv0 = (float)ht[0], bv1 = (float)ht[1];
                float bv2 = (float)ht[2], bv3 = (float)ht[3];
                if constexpr (BASEBN) {
                    const float4 p4 = *(const float4*)(ab2a + i);
                    const float4 q4 = *(const float4*)(ab2b + i);
                    bv0 = fmaxf(fmaf(bv0, p4.x, q4.x), 0.f);
                    bv1 = fmaxf(fmaf(bv1, p4.y, q4.y), 0.f);
                    bv2 = fmaxf(fmaf(bv2, p4.z, q4.z), 0.f);
                    bv3 = fmaxf(fmaf(bv3, p4.w, q4.w), 0.f);
                }
                h[0] = (__bf16)(fmaf((float)hy[0], a4.x, b4.x) + bv0);
                h[1] = (__bf16)(fmaf((float)hy[1], a4.y, b4.y) + bv1);
                h[2] = (__bf16)(fmaf((float)hy[2], a4.z, b4.z) + bv2);
                h[3] = (__bf16)(fmaf((float)hy[3], a4.w, b4.w) + bv3);
                if constexpr (WRITEBACK)
                    *(bf16x4*)(wbk + (size_t)(m0 + r) * FIN + i) = h;
            } else if constexpr (INBF) {
                const __bf16* src = (kk == 0) ? (const __bf16*)x0
                                  : (kk == 1 ? (const __bf16*)x1 : (const __bf16*)x2);
                bf16x4 hv = *(const bf16x4*)(src + (size_t)(m0 + r) * FIN + i);
                if (BN0 && (NSRC == 1 || kk == 0)) {
                    const float4 a4 = *(const float4*)(ab1a + i);
                    const float4 b4 = *(const float4*)(ab1b + i);
                    h[0] = (__bf16)fmaxf(fmaf((float)hv[0], a4.x, b4.x), 0.f);
                    h[1] = (__bf16)fmaxf(fmaf((float)hv[1], a4.y, b4.y), 0.f);
                    h[2] = (__bf16)fmaxf(fmaf((float)hv[2], a4.z, b4.z), 0.f);
                    h[3] = (__bf16)fmaxf(fmaf((float)hv[3], a4.w, b4.w), 0.f);
                } else {
                    h = hv;
                }
            } else {
                const float* src = (kk == 0) ? (const float*)x0
                                 : (kk == 1 ? (const float*)x1 : (const float*)x2);
                float4 v = *(const float4*)(src + (size_t)(m0 + r) * FIN + i);
                if (BN0 && (NSRC == 1 || kk == 0)) {
                    const float4 a4 = *(const float4*)(ab1a + i);
                    const float4 b4 = *(const float4*)(ab1b + i);
                    v.x = fmaxf(fmaf(v.x, a4.x, b4.x), 0.f);
                    v.y = fmaxf(fmaf(v.y, a4.y, b4.y), 0.f);
                    v.z = fmaxf(fmaf(v.z, a4.z, b4.z), 0.f);
                    v.w = fmaxf(fmaf(v.w, a4.w, b4.w), 0.f);
                }
                h[0] = (__bf16)v.x; h[1] = (__bf16)v.y; h[2] = (__bf16)v.z; h[3] = (__bf16)v.w;
            }
        } else {
            h[0] = (__bf16)0.f; h[1] = (__bf16)0.f; h[2] = (__bf16)0.f; h[3] = (__bf16)0.f;
        }
        *(bf16x4*)(xs + (size_t)r * LDKB + ki) = h;
    }
    __syncthreads();

    const int lane = tid & 63;
    const int wv   = tid >> 6;
    const int lo   = lane & 15;
    const int hi   = lane >> 4;

    if constexpr (COLS) {
        f32x4 acc[4][NT2];
        #pragma unroll
        for (int mr = 0; mr < 4; ++mr)
            #pragma unroll
            for (int n = 0; n < NT2; ++n) acc[mr][n] = (f32x4){0.f, 0.f, 0.f, 0.f};

        #pragma unroll
        for (int ks = 0; ks < NSTEP; ++ks) {
            bf16x8 bfr[NT2];
            #pragma unroll
            for (int n = 0; n < NT2; ++n)
                bfr[n] = *(const bf16x8*)(wp + ((size_t)(ks * NT + wv * NT2 + n) * 64 + lane) * 8);
            bf16x8 afr[4];
            #pragma unroll
            for (int mr = 0; mr < 4; ++mr)
                afr[mr] = *(const bf16x8*)(xs + (size_t)(mr * 16 + lo) * LDKB + ks * 32 + hi * 8);
            #pragma unroll
            for (int n = 0; n < NT2; ++n)
                #pragma unroll
                for (int mr = 0; mr < 4; ++mr)
                    acc[mr][n] = __builtin_amdgcn_mfma_f32_16x16x32_bf16(afr[mr], bfr[n], acc[mr][n], 0, 0, 0);
        }

        #pragma unroll
        for (int n = 0; n < NT2; ++n) {
            const int o = wv * (FOUT / 4) + n * 16 + lo;
            const float bo = HAS_BIAS ? bias[o] : 0.f;
            #pragma unroll
            for (int mr = 0; mr < 4; ++mr)
                #pragma unroll
                for (int j = 0; j < 4; ++j) acc[mr][n][j] += bo;
        }

        if constexpr (STATS) {
            #pragma unroll
            for (int n = 0; n < NT2; ++n) {
                float s = 0.f, q = 0.f;
                #pragma unroll
                for (int mr = 0; mr < 4; ++mr)
                    #pragma unroll
                    for (int j = 0; j < 4; ++j) {
                        const float v = acc[mr][n][j];
                        s += v; q = fmaf(v, v, q);
                    }
                s += __shfl_xor(s, 16); q += __shfl_xor(q, 16);
                s += __shfl_xor(s, 32); q += __shfl_xor(q, 32);
                if (lane < 16) {
                    const int o = wv * (FOUT / 4) + n * 16 + lo;
                    atomicAdd(&stats_out[o], s);
                    atomicAdd(&stats_out[256 + o], q);
                }
            }
        }

        float* cs = (float*)smem;
        #pragma unroll
        for (int mr = 0; mr < 4; ++mr) {
            __syncthreads();
            #pragma unroll
            for (int n = 0; n < NT2; ++n) {
                const int o = wv * (FOUT / 4) + n * 16 + lo;
                #pragma unroll
                for (int j = 0; j < 4; ++j)
                    cs[(size_t)(hi * 4 + j) * LDC + o] = acc[mr][n][j];
            }
            __syncthreads();
            for (int t = tid; t < 16 * (FOUT / 4); t += 256) {
                const int rr = t / (FOUT / 4);
                const int c4 = (t % (FOUT / 4)) * 4;
                const float4 v = *(const float4*)(cs + (size_t)rr * LDC + c4);
                if constexpr (OUTBF) {
                    bf16x4 hv;
                    hv[0] = (__bf16)v.x; hv[1] = (__bf16)v.y;
                    hv[2] = (__bf16)v.z; hv[3] = (__bf16)v.w;
                    *(bf16x4*)((__bf16*)out + (size_t)(m0 + mr * 16 + rr) * FOUT + c4) = hv;
                } else {
                    *(float4*)((float*)out + (size_t)(m0 + mr * 16 + rr) * FOUT + c4) = v;
                }
            }
        }
    } else {
        f32x4 acc[NT];
        #pragma unroll
        for (int nt = 0; nt < NT; ++nt) acc[nt] = (f32x4){0.f, 0.f, 0.f, 0.f};
        const int arow = wv * 16 + lo;
        #pragma unroll
        for (int ks = 0; ks < NSTEP; ++ks) {
            const bf16x8 a = *(const bf16x8*)(xs + (size_t)arow * LDKB + ks * 32 + hi * 8);
            #pragma unroll
            for (int nt = 0; nt < NT; ++nt) {
                const bf16x8 b = *(const bf16x8*)(wp + ((size_t)(ks * NT + nt) * 64 + lane) * 8);
                acc[nt] = __builtin_amdgcn_mfma_f32_16x16x32_bf16(a, b, acc[nt], 0, 0, 0);
            }
        }
        #pragma unroll
        for (int nt = 0; nt < NT; ++nt) {
            const int o = nt * 16 + lo;
            const float bo = HAS_BIAS ? bias[o] : 0.f;
            #pragma unroll
            for (int j = 0; j < 4; ++j) {
                const float v = acc[nt][j] + bo;
                const int m = m0 + wv * 16 + hi * 4 + j;
                if constexpr (PACKOUT) {
                    const int zj = o >> 3;
                    if (zj < 3) ((float*)out)[((size_t)zj * BV + m) * 8 + (o & 7)] = v;
                } else {
                    ((float*)out)[(size_t)m * FOUT + o] = v;
                }
            }
        }
    }
}

extern "C" void kernel_launch(void* const* d_in, const int* in_sizes, int n_in,
                              void* d_out, int out_size, void* d_ws, size_t ws_size,
                              hipStream_t stream)
{
    const float* x       = (const float*)d_in[0];
    const int*   col     = (const int*)  d_in[2];
    const float* eval_   = (const float*)d_in[3];
    const float* conv1_w = (const float*)d_in[4];
    const float* conv1_b = (const float*)d_in[5];
    const float* bn1_g   = (const float*)d_in[6];
    const float* bn1_b   = (const float*)d_in[7];
    const float* conv2_w = (const float*)d_in[8];
    const float* conv2_b = (const float*)d_in[9];
    const float* bn2_g   = (const float*)d_in[10];
    const float* bn2_b   = (const float*)d_in[11];
    const float* bt_c1w  = (const float*)d_in[12];
    const float* bt_c1b  = (const float*)d_in[13];
    const float* bt_c2w  = (const float*)d_in[14];
    const float* bt_c2b  = (const float*)d_in[15];
    const float* bt_c3w  = (const float*)d_in[16];
    const float* bt_c3b  = (const float*)d_in[17];
    const float* btbn1g  = (const float*)d_in[18];
    const float* btbn1b  = (const float*)d_in[19];
    const float* btbn2g  = (const float*)d_in[20];
    const float* btbn2b  = (const float*)d_in[21];
    const float* btbn3g  = (const float*)d_in[22];
    const float* btbn3b  = (const float*)d_in[23];
    const float* conv3_w = (const float*)d_in[24];
    const float* conv3_b = (const float*)d_in[25];
    float* out = (float*)d_out;

    __bf16* h2b  = (__bf16*)d_ws;                  // BV*256 bf16 (trunk)
    __bf16* y3b  = h2b + (size_t)BV * 256;         // BV*256 bf16 (cheb3 out)
    __bf16* t64a = y3b + (size_t)BV * 256;         // 4 x BV*64 bf16
    __bf16* t64b = t64a + (size_t)BV * 64;
    __bf16* t64c = t64b + (size_t)BV * 64;
    __bf16* t64d = t64c + (size_t)BV * 64;
    float*  scr  = (float*)(t64d + (size_t)BV * 64);   // BV*32 fp32
    float*  bpack = scr + (size_t)BV * 32;         // 32
    __bf16* wb   = (__bf16*)(bpack + 32);          // bf16 weight arena
    __bf16* wp1  = wb;                             // 2048
    __bf16* wp2  = wp1 + 2048;                     // 49152
    __bf16* wpc1 = wp2 + 49152;                    // 49152
    __bf16* wpc2 = wpc1 + 49152;                   // 36864
    __bf16* wpc3 = wpc2 + 36864;                   // 49152
    __bf16* wp3  = wpc3 + 49152;                   // 8192
    float*  stats = (float*)(wp3 + 8192);          // 11 stages x 512 floats
    int2*   edges = (int2*)(stats + 11 * 512);     // NE (2 MB)

    float* t8a = scr;                              // BV*8 (stage A)
    float* t8b = scr + (size_t)BV * 8;

    const float invN = 1.f / (float)BV;
    const int NGB  = BV / 64;                      // 768
    const int NSP64 = BV * 8 / 256;                // 1536
    const int NSP8  = BV * 2 / 256;                // 384

    // stage bases: 0=BN1, 1=BN2, 2+3i=btbn1_i, 3+3i=btbn2_i, 4+3i=btbn3_i
    float* ST0 = stats;
    float* ST1 = stats + 512;

    hipMemsetAsync(stats, 0, 11 * 512 * sizeof(float), stream);

    // ---------- packing: 1 launch ----------
    pack_all_kernel<<<1769, 256, 0, stream>>>(conv1_w, conv2_w, bt_c1w, bt_c2w, bt_c3w,
                                              conv3_w, conv3_b, eval_, col, wb, bpack, edges);

    // ---------- Stage A: conv1 (8 -> 64), folded: t8a = Lx, t8b = L t8a ----------
    spmm8_kernel<0><<<NSP8, 256, 0, stream>>>(t8a, x, nullptr, edges);
    spmm8_kernel<0><<<NSP8, 256, 0, stream>>>(t8b, t8a, nullptr, edges);
    gemm_mfma_kernel<64, 24, 32, 8, 3, true, false, true, false, false, true>
        <<<NGB, 256, 0, stream>>>(x, t8a, t8b, wp1, conv1_b,
                                  nullptr, nullptr, nullptr, nullptr, nullptr, nullptr,
                                  t64c, ST0, nullptr, invN);

    // ---------- Stage B: conv2 (64 -> 256); t64a = L relu(BN1 h), t64b = L t64a ----
    spmm64_kernel<true ><<<NSP64, 256, 0, stream>>>(t64a, t64c, edges, ST0, bn1_g, bn1_b, invN);
    spmm64_kernel<false><<<NSP64, 256, 0, stream>>>(t64b, t64a, edges, nullptr, nullptr, nullptr, invN);
    gemm_mfma_kernel<256, 192, 192, 64, 3, true, true, true, false, true, true>
        <<<NGB, 256, 0, stream>>>(t64c, t64a, t64b, wp2, conv2_b,
                                  ST0, bn1_g, bn1_b, nullptr, nullptr, nullptr,
                                  h2b, ST1, nullptr, invN);

    // ---------- Stage C: 3 bottlenecks ----------
    for (int i = 0; i < 3; ++i) {
        float* STA = stats + (2 + i * 3) * 512;   // btbn1_i
        float* STB = stats + (3 + i * 3) * 512;   // btbn2_i
        float* STC = stats + (4 + i * 3) * 512;   // btbn3_i

        // cheb1: 256->64; i=0: BN2 fused; i>=1: fused trunk update (RESID [+BASEBN]).
        if (i == 0)
            gemm_mfma_kernel<64, 256, 256, 256, 1, true, true, true, false, true, true>
                <<<NGB, 256, 0, stream>>>(h2b, nullptr, nullptr, wpc1, bt_c1b,
                                          ST1, bn2_g, bn2_b, nullptr, nullptr, nullptr,
                                          t64c, STA, nullptr, invN);
        else if (i == 1)
            gemm_mfma_kernel<64, 256, 256, 256, 1, true, false, true, false, true, true, true, true, true>
                <<<NGB, 256, 0, stream>>>(y3b, h2b, nullptr, wpc1 + (size_t)1 * 16384, bt_c1b + 64,
                                          stats + 4 * 512, btbn3g, btbn3b,       // BN3_0
                                          ST1, bn2_g, bn2_b,                     // BN2 (BASEBN)
                                          t64c, STA, h2b, invN);
        else
            gemm_mfma_kernel<64, 256, 256, 256, 1, true, false, true, false, true, true, true, false, true>
                <<<NGB, 256, 0, stream>>>(y3b, h2b, nullptr, wpc1 + (size_t)2 * 16384, bt_c1b + 128,
                                          stats + 7 * 512, btbn3g + 256, btbn3b + 256,  // BN3_1
                                          nullptr, nullptr, nullptr,
                                          t64c, STA, h2b, invN);

        // cheb2: t64a = L relu(BN(t64c)), t64b = L t64a (folded weights)
        spmm64_kernel<true ><<<NSP64, 256, 0, stream>>>(t64a, t64c, edges, STA, btbn1g + i * 64, btbn1b + i * 64, invN);
        spmm64_kernel<false><<<NSP64, 256, 0, stream>>>(t64b, t64a, edges, nullptr, nullptr, nullptr, invN);
        gemm_mfma_kernel<64, 192, 192, 64, 3, true, true, true, false, true, true>
            <<<NGB, 256, 0, stream>>>(t64c, t64a, t64b, wpc2 + (size_t)i * 12288, bt_c2b + i * 64,
                                      STA, btbn1g + i * 64, btbn1b + i * 64, nullptr, nullptr, nullptr,
                                      t64d, STB, nullptr, invN);

        // cheb3: 64->256 (BN2-of-bottleneck fused on staging), y3b bf16 out
        gemm_mfma_kernel<256, 64, 64, 64, 1, true, true, true, false, true, true>
            <<<NGB, 256, 0, stream>>>(t64d, nullptr, nullptr, wpc3 + (size_t)i * 16384, bt_c3b + i * 256,
                                      STB, btbn2g + i * 64, btbn2b + i * 64, nullptr, nullptr, nullptr,
                                      y3b, STC, nullptr, invN);
    }

    // ---------- Stage D: conv3, folded weights + fused final residual ----------
    float* z0 = scr;
    float* z1 = z0 + (size_t)BV * 8;
    float* z2 = z1 + (size_t)BV * 8;
    float* ee = z2 + (size_t)BV * 8;

    gemm_mfma_kernel<32, 256, 256, 256, 1, false, true, true, true, true, false, true>
        <<<NGB, 256, 0, stream>>>(y3b, h2b, nullptr, wp3, bpack,
                                  stats + 10 * 512, btbn3g + 512, btbn3b + 512,  // BN3_2
                                  nullptr, nullptr, nullptr,
                                  z0, nullptr, nullptr, invN);

    spmm8_kernel<2><<<NSP8, 256, 0, stream>>>(ee, z2, z1, edges);
    spmm8_kernel<2><<<NSP8, 256, 0, stream>>>(out, ee, z0, edges);

    (void)in_sizes; (void)n_in; (void)out_size; (void)ws_size;
}

// Round 23
// 290.935 us; speedup vs baseline: 1.3495x; 1.3495x over previous
//
#include <hip/hip_runtime.h>

static constexpr int NBRS = 21;
static constexpr int Nv   = 12288;
static constexpr int BV   = 4 * Nv;            // 49152 rows
static constexpr int NE   = Nv * NBRS;         // 258048 edges
static constexpr float BN_EPS = 1e-5f;

typedef __bf16 bf16x4 __attribute__((ext_vector_type(4)));
typedef __bf16 bf16x8 __attribute__((ext_vector_type(8)));
typedef float  f32x4  __attribute__((ext_vector_type(4)));

__device__ __forceinline__ int xcd_swz(int bid, int grid)
{
    // bijective chunked XCD swizzle (grid % 8 == 0)
    return (bid & 7) * (grid >> 3) + (bid >> 3);
}

// ---------------- SPMM (C=8, fp32, float4: 2 threads/row).
// MODE 0: y = acc; MODE 2: y = acc + x0.
template<int MODE>
__global__ __launch_bounds__(256)
void spmm8_kernel(float* __restrict__ y, const float* __restrict__ x,
                  const float* __restrict__ x0,
                  const int2* __restrict__ edges)
{
    int idx = xcd_swz(blockIdx.x, gridDim.x) * 256 + threadIdx.x;   // over BV*2
    int c4 = idx & 1;
    int row = idx >> 1;
    int v = row % Nv;
    int b = row / Nv;
    int e0 = v * NBRS;
    const float4* x4 = (const float4*)x;
    float4 acc = {0.f, 0.f, 0.f, 0.f};
    #pragma unroll
    for (int j = 0; j < NBRS; ++j) {
        const int2 ed = edges[e0 + j];
        const float a = __int_as_float(ed.x);
        const int u = ed.y;
        float4 xv = x4[(size_t)(b * Nv + u) * 2 + c4];
        acc.x = fmaf(a, xv.x, acc.x);
        acc.y = fmaf(a, xv.y, acc.y);
        acc.z = fmaf(a, xv.z, acc.z);
        acc.w = fmaf(a, xv.w, acc.w);
    }
    if (MODE == 2) {
        float4 p = ((const float4*)x0)[idx];
        acc.x += p.x; acc.y += p.y; acc.z += p.z; acc.w += p.w;
    }
    ((float4*)y)[idx] = acc;
}

// ---------------- SPMM C=64, bf16x8 (16B) per thread, 8 threads/row.
// BNG: apply relu(BN(.)) to gathered elements.
template<bool BNG>
__global__ __launch_bounds__(256)
void spmm64_kernel(__bf16* __restrict__ y, const __bf16* __restrict__ x,
                   const int2* __restrict__ edges,
                   const float* __restrict__ bn_a, const float* __restrict__ bn_b)
{
    int idx = xcd_swz(blockIdx.x, gridDim.x) * 256 + threadIdx.x;   // over BV*8
    int q = idx % 8;
    int v = (idx / 8) % Nv;
    int b = idx / (8 * Nv);
    int e0 = v * NBRS;
    const bf16x8* x8 = (const bf16x8*)x;
    float4 aL, aH, bL, bH;
    if (BNG) {
        aL = ((const float4*)bn_a)[q * 2];     aH = ((const float4*)bn_a)[q * 2 + 1];
        bL = ((const float4*)bn_b)[q * 2];     bH = ((const float4*)bn_b)[q * 2 + 1];
    }
    float acc[8];
    #pragma unroll
    for (int t = 0; t < 8; ++t) acc[t] = 0.f;
    #pragma unroll
    for (int j = 0; j < NBRS; ++j) {
        const int2 ed = edges[e0 + j];
        const float a = __int_as_float(ed.x);
        const int u = ed.y;
        bf16x8 hv = x8[(size_t)(b * Nv + u) * 8 + q];
        float xv[8];
        #pragma unroll
        for (int t = 0; t < 8; ++t) xv[t] = (float)hv[t];
        if (BNG) {
            xv[0] = fmaxf(fmaf(xv[0], aL.x, bL.x), 0.f);
            xv[1] = fmaxf(fmaf(xv[1], aL.y, bL.y), 0.f);
            xv[2] = fmaxf(fmaf(xv[2], aL.z, bL.z), 0.f);
            xv[3] = fmaxf(fmaf(xv[3], aL.w, bL.w), 0.f);
            xv[4] = fmaxf(fmaf(xv[4], aH.x, bH.x), 0.f);
            xv[5] = fmaxf(fmaf(xv[5], aH.y, bH.y), 0.f);
            xv[6] = fmaxf(fmaf(xv[6], aH.z, bH.z), 0.f);
            xv[7] = fmaxf(fmaf(xv[7], aH.w, bH.w), 0.f);
        }
        #pragma unroll
        for (int t = 0; t < 8; ++t) acc[t] = fmaf(a, xv[t], acc[t]);
    }
    bf16x8 o;
    #pragma unroll
    for (int t = 0; t < 8; ++t) o[t] = (__bf16)acc[t];
    ((bf16x8*)y)[idx] = o;
}

// ---------------- unified pack with Chebyshev folding + edge packing.
// Weights: K=3 regions -> (W0 - W2), W1, 2*W2. Edge list: (val, col) interleaved.
__global__ __launch_bounds__(256)
void pack_all_kernel(const float* __restrict__ w1, const float* __restrict__ w2,
                     const float* __restrict__ c1, const float* __restrict__ c2,
                     const float* __restrict__ c3, const float* __restrict__ w3,
                     const float* __restrict__ b3,
                     const float* __restrict__ eval_, const int* __restrict__ col,
                     __bf16* __restrict__ wb, float* __restrict__ bpack,
                     int2* __restrict__ edges)
{
    int t = blockIdx.x * 256 + threadIdx.x;
    if (t >= 194560) {
        int i = t - 194560;
        if (i < 32) { bpack[i] = (i < 8) ? b3[i] : 0.f; return; }
        int e = t - 194592;
        if (e < NE) edges[e] = make_int2(__float_as_int(eval_[e]), col[e]);
        return;
    }
    const float* src; int KSRC, FOUT, FIN, local; bool fold = false, isW3 = false;
    if (t < 2048)        { src = w1;  KSRC = 24;  FOUT = 64;  FIN = 8;  local = t; fold = true; }
    else if (t < 51200)  { src = w2;  KSRC = 192; FOUT = 256; FIN = 64; local = t - 2048; fold = true; }
    else if (t < 100352) { int i = (t - 51200) / 16384;  src = c1 + (size_t)i * 16384;
                           KSRC = 256; FOUT = 64;  FIN = 256; local = (t - 51200) % 16384; }
    else if (t < 137216) { int i = (t - 100352) / 12288; src = c2 + (size_t)i * 12288;
                           KSRC = 192; FOUT = 64;  FIN = 64; local = (t - 100352) % 12288; fold = true; }
    else if (t < 186368) { int i = (t - 137216) / 16384; src = c3 + (size_t)i * 16384;
                           KSRC = 64;  FOUT = 256; FIN = 64; local = (t - 137216) % 16384; }
    else                 { src = w3;  KSRC = 256; FOUT = 32; FIN = 256; local = t - 186368; isW3 = true; }
    const int j    = local & 7;
    const int lane = (local >> 3) & 63;
    const int rest = local >> 9;
    const int NT = FOUT >> 4;
    const int nt = rest % NT;
    const int ks = rest / NT;
    const int k = ks * 32 + (lane >> 4) * 8 + j;
    const int o = nt * 16 + (lane & 15);
    float v = 0.f;
    if (isW3) {
        const int zj = o >> 3, oo = o & 7;
        if (zj == 0)      v = src[(size_t)k * 8 + oo] - src[(size_t)2 * 2048 + k * 8 + oo];
        else if (zj == 1) v = src[(size_t)2048 + k * 8 + oo];
        else if (zj == 2) v = 2.f * src[(size_t)2 * 2048 + k * 8 + oo];
    } else if (k < KSRC) {
        if (fold) {
            if (k < FIN)          v = src[(size_t)k * FOUT + o] - src[(size_t)(k + 2 * FIN) * FOUT + o];
            else if (k < 2 * FIN) v = src[(size_t)k * FOUT + o];
            else                  v = 2.f * src[(size_t)k * FOUT + o];
        } else {
            v = src[(size_t)k * FOUT + o];
        }
    }
    wb[t] = (__bf16)v;
}

// ---------------- MFMA GEMM. INBF: x bf16; OUTBF: write bf16.
// RESID (NSRC=1, INBF): stage = BN(x0) + base(x1) (BASEBN: relu(BN2(base))),
// optionally WRITEBACK the staged value to wbk (trunk update).
template<int FOUT, int KFIN, int KPAD, int FIN, int NSRC,
         bool STATS, bool BN0, bool HAS_BIAS, bool PACKOUT, bool INBF, bool OUTBF,
         bool RESID = false, bool BASEBN = false, bool WRITEBACK = false>
__global__ __launch_bounds__(256)
void gemm_mfma_kernel(const void* __restrict__ x0, const void* __restrict__ x1,
                      const void* __restrict__ x2,
                      const __bf16* __restrict__ wp, const float* __restrict__ bias,
                      const float* __restrict__ bn_a, const float* __restrict__ bn_b,
                      const float* __restrict__ bn_a2, const float* __restrict__ bn_b2,
                      void* __restrict__ out, float2* __restrict__ partial,
                      __bf16* __restrict__ wbk)
{
    constexpr int NT    = FOUT / 16;
    constexpr int NSTEP = KPAD / 32;
    constexpr bool COLS = (NT % 4 == 0);
    constexpr int NT2   = COLS ? NT / 4 : NT;
    constexpr int LDKB  = KPAD + 8;
    constexpr int LDC   = FOUT + 4;
    constexpr size_t XS_B  = (size_t)64 * LDKB * 2;
    constexpr size_t RPK_B = COLS ? (size_t)16 * LDC * 4 : 0;
    constexpr size_t SMEM  = XS_B > RPK_B ? XS_B : RPK_B;
    __shared__ __align__(16) char smem[SMEM];
    __bf16* xs = (__bf16*)smem;

    const int tid = threadIdx.x;
    const int m0 = blockIdx.x * 64;

    constexpr int NF4 = 64 * (KPAD / 4);
    for (int f = tid; f < NF4; f += 256) {
        const int r  = f / (KPAD / 4);
        const int ki = (f % (KPAD / 4)) * 4;
        bf16x4 h;
        if (KFIN == KPAD || ki < KFIN) {
            int i; int kk;
            if constexpr (NSRC == 1) { i = ki; kk = 0; }
            else { kk = ki / FIN; i = ki % FIN; }
            if constexpr (RESID) {
                const __bf16* srcy = (const __bf16*)x0;
                const __bf16* srct = (const __bf16*)x1;
                bf16x4 hy = *(const bf16x4*)(srcy + (size_t)(m0 + r) * FIN + i);
                bf16x4 ht = *(const bf16x4*)(srct + (size_t)(m0 + r) * FIN + i);
                const float4 a4 = *(const float4*)(bn_a + i);
                const float4 b4 = *(const float4*)(bn_b + i);
                float bv0 = (float)ht[0], bv1 = (float)ht[1];
                float bv2 = (float)ht[2], bv3 = (float)ht[3];
                if constexpr (BASEBN) {
                    const float4 p4 = *(const float4*)(bn_a2 + i);
                    const float4 q4 = *(const float4*)(bn_b2 + i);
                    bv0 = fmaxf(fmaf(bv0, p4.x, q4.x), 0.f);
                    bv1 = fmaxf(fmaf(bv1, p4.y, q4.y), 0.f);
                    bv2 = fmaxf(fmaf(bv2, p4.z, q4.z), 0.f);
                    bv3 = fmaxf(fmaf(bv3, p4.w, q4.w), 0.f);
                }
                h[0] = (__bf16)(fmaf((float)hy[0], a4.x, b4.x) + bv0);
                h[1] = (__bf16)(fmaf((float)hy[1], a4.y, b4.y) + bv1);
                h[2] = (__bf16)(fmaf((float)hy[2], a4.z, b4.z) + bv2);
                h[3] = (__bf16)(fmaf((float)hy[3], a4.w, b4.w) + bv3);
                if constexpr (WRITEBACK)
                    *(bf16x4*)(wbk + (size_t)(m0 + r) * FIN + i) = h;
            } else if constexpr (INBF) {
                const __bf16* src = (kk == 0) ? (const __bf16*)x0
                                  : (kk == 1 ? (const __bf16*)x1 : (const __bf16*)x2);
                bf16x4 hv = *(const bf16x4*)(src + (size_t)(m0 + r) * FIN + i);
                if (BN0 && (NSRC == 1 || kk == 0)) {
                    const float4 a4 = *(const float4*)(bn_a + i);
                    const float4 b4 = *(const float4*)(bn_b + i);
                    h[0] = (__bf16)fmaxf(fmaf((float)hv[0], a4.x, b4.x), 0.f);
                    h[1] = (__bf16)fmaxf(fmaf((float)hv[1], a4.y, b4.y), 0.f);
                    h[2] = (__bf16)fmaxf(fmaf((float)hv[2], a4.z, b4.z), 0.f);
                    h[3] = (__bf16)fmaxf(fmaf((float)hv[3], a4.w, b4.w), 0.f);
                } else {
                    h = hv;
                }
            } else {
                const float* src = (kk == 0) ? (const float*)x0
                                 : (kk == 1 ? (const float*)x1 : (const float*)x2);
                float4 v = *(const float4*)(src + (size_t)(m0 + r) * FIN + i);
                if (BN0 && (NSRC == 1 || kk == 0)) {
                    const float4 a4 = *(const float4*)(bn_a + i);
                    const float4 b4 = *(const float4*)(bn_b + i);
                    v.x = fmaxf(fmaf(v.x, a4.x, b4.x), 0.f);
                    v.y = fmaxf(fmaf(v.y, a4.y, b4.y), 0.f);
                    v.z = fmaxf(fmaf(v.z, a4.z, b4.z), 0.f);
                    v.w = fmaxf(fmaf(v.w, a4.w, b4.w), 0.f);
                }
                h[0] = (__bf16)v.x; h[1] = (__bf16)v.y; h[2] = (__bf16)v.z; h[3] = (__bf16)v.w;
            }
        } else {
            h[0] = (__bf16)0.f; h[1] = (__bf16)0.f; h[2] = (__bf16)0.f; h[3] = (__bf16)0.f;
        }
        *(bf16x4*)(xs + (size_t)r * LDKB + ki) = h;
    }
    __syncthreads();

    const int lane = tid & 63;
    const int wv   = tid >> 6;
    const int lo   = lane & 15;
    const int hi   = lane >> 4;

    if constexpr (COLS) {
        f32x4 acc[4][NT2];
        #pragma unroll
        for (int mr = 0; mr < 4; ++mr)
            #pragma unroll
            for (int n = 0; n < NT2; ++n) acc[mr][n] = (f32x4){0.f, 0.f, 0.f, 0.f};

        #pragma unroll
        for (int ks = 0; ks < NSTEP; ++ks) {
            bf16x8 bfr[NT2];
            #pragma unroll
            for (int n = 0; n < NT2; ++n)
                bfr[n] = *(const bf16x8*)(wp + ((size_t)(ks * NT + wv * NT2 + n) * 64 + lane) * 8);
            bf16x8 afr[4];
            #pragma unroll
            for (int mr = 0; mr < 4; ++mr)
                afr[mr] = *(const bf16x8*)(xs + (size_t)(mr * 16 + lo) * LDKB + ks * 32 + hi * 8);
            #pragma unroll
            for (int n = 0; n < NT2; ++n)
                #pragma unroll
                for (int mr = 0; mr < 4; ++mr)
                    acc[mr][n] = __builtin_amdgcn_mfma_f32_16x16x32_bf16(afr[mr], bfr[n], acc[mr][n], 0, 0, 0);
        }

        #pragma unroll
        for (int n = 0; n < NT2; ++n) {
            const int o = wv * (FOUT / 4) + n * 16 + lo;
            const float bo = HAS_BIAS ? bias[o] : 0.f;
            #pragma unroll
            for (int mr = 0; mr < 4; ++mr)
                #pragma unroll
                for (int j = 0; j < 4; ++j) acc[mr][n][j] += bo;
        }

        if constexpr (STATS) {
            #pragma unroll
            for (int n = 0; n < NT2; ++n) {
                float s = 0.f, q = 0.f;
                #pragma unroll
                for (int mr = 0; mr < 4; ++mr)
                    #pragma unroll
                    for (int j = 0; j < 4; ++j) {
                        const float v = acc[mr][n][j];
                        s += v; q = fmaf(v, v, q);
                    }
                s += __shfl_xor(s, 16); q += __shfl_xor(q, 16);
                s += __shfl_xor(s, 32); q += __shfl_xor(q, 32);
                if (lane < 16) {
                    const int o = wv * (FOUT / 4) + n * 16 + lo;
                    partial[(size_t)o * gridDim.x + blockIdx.x] = make_float2(s, q);
                }
            }
        }

        float* cs = (float*)smem;
        #pragma unroll
        for (int mr = 0; mr < 4; ++mr) {
            __syncthreads();
            #pragma unroll
            for (int n = 0; n < NT2; ++n) {
                const int o = wv * (FOUT / 4) + n * 16 + lo;
                #pragma unroll
                for (int j = 0; j < 4; ++j)
                    cs[(size_t)(hi * 4 + j) * LDC + o] = acc[mr][n][j];
            }
            __syncthreads();
            for (int t = tid; t < 16 * (FOUT / 4); t += 256) {
                const int rr = t / (FOUT / 4);
                const int c4 = (t % (FOUT / 4)) * 4;
                const float4 v = *(const float4*)(cs + (size_t)rr * LDC + c4);
                if constexpr (OUTBF) {
                    bf16x4 hv;
                    hv[0] = (__bf16)v.x; hv[1] = (__bf16)v.y;
                    hv[2] = (__bf16)v.z; hv[3] = (__bf16)v.w;
                    *(bf16x4*)((__bf16*)out + (size_t)(m0 + mr * 16 + rr) * FOUT + c4) = hv;
                } else {
                    *(float4*)((float*)out + (size_t)(m0 + mr * 16 + rr) * FOUT + c4) = v;
                }
            }
        }
    } else {
        f32x4 acc[NT];
        #pragma unroll
        for (int nt = 0; nt < NT; ++nt) acc[nt] = (f32x4){0.f, 0.f, 0.f, 0.f};
        const int arow = wv * 16 + lo;
        #pragma unroll
        for (int ks = 0; ks < NSTEP; ++ks) {
            const bf16x8 a = *(const bf16x8*)(xs + (size_t)arow * LDKB + ks * 32 + hi * 8);
            #pragma unroll
            for (int nt = 0; nt < NT; ++nt) {
                const bf16x8 b = *(const bf16x8*)(wp + ((size_t)(ks * NT + nt) * 64 + lane) * 8);
                acc[nt] = __builtin_amdgcn_mfma_f32_16x16x32_bf16(a, b, acc[nt], 0, 0, 0);
            }
        }
        #pragma unroll
        for (int nt = 0; nt < NT; ++nt) {
            const int o = nt * 16 + lo;
            const float bo = HAS_BIAS ? bias[o] : 0.f;
            #pragma unroll
            for (int j = 0; j < 4; ++j) {
                const float v = acc[nt][j] + bo;
                const int m = m0 + wv * 16 + hi * 4 + j;
                if constexpr (PACKOUT) {
                    const int zj = o >> 3;
                    if (zj < 3) ((float*)out)[((size_t)zj * BV + m) * 8 + (o & 7)] = v;
                } else {
                    ((float*)out)[(size_t)m * FOUT + o] = v;
                }
            }
        }
    }
}

// ---------------- BN finalize: one block per channel, coalesced over [C][nblk]
__global__ __launch_bounds__(256)
void bn_finalize_kernel(const float2* __restrict__ partial,
                        const float* __restrict__ g, const float* __restrict__ b,
                        float* __restrict__ a_out, float* __restrict__ b_out,
                        float invN, int nblk)
{
    __shared__ float2 red[4];
    const int c = blockIdx.x;
    const float2* p = partial + (size_t)c * nblk;
    float s = 0.f, ss = 0.f;
    for (int k = threadIdx.x; k < nblk; k += 256) {
        const float2 v = p[k];
        s += v.x; ss += v.y;
    }
    #pragma unroll
    for (int off = 32; off > 0; off >>= 1) {
        s  += __shfl_down(s, off);
        ss += __shfl_down(ss, off);
    }
    if ((threadIdx.x & 63) == 0) red[threadIdx.x >> 6] = make_float2(s, ss);
    __syncthreads();
    if (threadIdx.x == 0) {
        float ts = 0.f, tq = 0.f;
        #pragma unroll
        for (int i = 0; i < 4; ++i) { ts += red[i].x; tq += red[i].y; }
        const float m = ts * invN;
        const float var = tq * invN - m * m;
        const float a = g[c] * rsqrtf(var + BN_EPS);
        a_out[c] = a;
        b_out[c] = b[c] - m * a;
    }
}

extern "C" void kernel_launch(void* const* d_in, const int* in_sizes, int n_in,
                              void* d_out, int out_size, void* d_ws, size_t ws_size,
                              hipStream_t stream)
{
    const float* x       = (const float*)d_in[0];
    const int*   col     = (const int*)  d_in[2];
    const float* eval_   = (const float*)d_in[3];
    const float* conv1_w = (const float*)d_in[4];
    const float* conv1_b = (const float*)d_in[5];
    const float* bn1_g   = (const float*)d_in[6];
    const float* bn1_b   = (const float*)d_in[7];
    const float* conv2_w = (const float*)d_in[8];
    const float* conv2_b = (const float*)d_in[9];
    const float* bn2_g   = (const float*)d_in[10];
    const float* bn2_b   = (const float*)d_in[11];
    const float* bt_c1w  = (const float*)d_in[12];
    const float* bt_c1b  = (const float*)d_in[13];
    const float* bt_c2w  = (const float*)d_in[14];
    const float* bt_c2b  = (const float*)d_in[15];
    const float* bt_c3w  = (const float*)d_in[16];
    const float* bt_c3b  = (const float*)d_in[17];
    const float* btbn1g  = (const float*)d_in[18];
    const float* btbn1b  = (const float*)d_in[19];
    const float* btbn2g  = (const float*)d_in[20];
    const float* btbn2b  = (const float*)d_in[21];
    const float* btbn3g  = (const float*)d_in[22];
    const float* btbn3b  = (const float*)d_in[23];
    const float* conv3_w = (const float*)d_in[24];
    const float* conv3_b = (const float*)d_in[25];
    float* out = (float*)d_out;

    __bf16* h2b  = (__bf16*)d_ws;                  // BV*256 bf16 (trunk)
    __bf16* y3b  = h2b + (size_t)BV * 256;         // BV*256 bf16 (cheb3 out)
    __bf16* t64a = y3b + (size_t)BV * 256;         // 4 x BV*64 bf16
    __bf16* t64b = t64a + (size_t)BV * 64;
    __bf16* t64c = t64b + (size_t)BV * 64;
    __bf16* t64d = t64c + (size_t)BV * 64;
    float*  scr  = (float*)(t64d + (size_t)BV * 64);   // BV*32 fp32
    float*  aarr = scr + (size_t)BV * 32;          // 11*256
    float*  barr = aarr + 11 * 256;                // 11*256
    float*  bpack = barr + 11 * 256;               // 32
    __bf16* wb   = (__bf16*)(bpack + 32);          // bf16 weight arena
    __bf16* wp1  = wb;                             // 2048
    __bf16* wp2  = wp1 + 2048;                     // 49152
    __bf16* wpc1 = wp2 + 49152;                    // 49152
    __bf16* wpc2 = wpc1 + 49152;                   // 36864
    __bf16* wpc3 = wpc2 + 36864;                   // 49152
    __bf16* wp3  = wpc3 + 49152;                   // 8192
    float2* part = (float2*)(wp3 + 8192);          // 256 * 768
    int2*   edges = (int2*)(part + 256 * 768);     // NE (2 MB)

    float* t8a = scr;                              // BV*8 (stage A)
    float* t8b = scr + (size_t)BV * 8;

    const float invN = 1.f / (float)BV;
    const int NGB  = BV / 64;                      // 768
    const int NSP64 = BV * 8 / 256;                // 1536
    const int NSP8  = BV * 2 / 256;                // 384

    // ---------- packing: 1 launch (cheb-folded weights + edge list) ----------
    pack_all_kernel<<<1769, 256, 0, stream>>>(conv1_w, conv2_w, bt_c1w, bt_c2w, bt_c3w,
                                              conv3_w, conv3_b, eval_, col, wb, bpack, edges);

    // ---------- Stage A: conv1 (8 -> 64), folded: t8a = Lx, t8b = L t8a ----------
    spmm8_kernel<0><<<NSP8, 256, 0, stream>>>(t8a, x, nullptr, edges);
    spmm8_kernel<0><<<NSP8, 256, 0, stream>>>(t8b, t8a, nullptr, edges);
    gemm_mfma_kernel<64, 24, 32, 8, 3, true, false, true, false, false, true>
        <<<NGB, 256, 0, stream>>>(x, t8a, t8b, wp1, conv1_b, nullptr, nullptr, nullptr, nullptr,
                                  t64c, part, nullptr);
    bn_finalize_kernel<<<64, 256, 0, stream>>>(part, bn1_g, bn1_b, aarr, barr, invN, NGB);

    // ---------- Stage B: conv2 (64 -> 256); t64a = L h, t64b = L t64a ----------
    spmm64_kernel<true ><<<NSP64, 256, 0, stream>>>(t64a, t64c, edges, aarr, barr);
    spmm64_kernel<false><<<NSP64, 256, 0, stream>>>(t64b, t64a, edges, nullptr, nullptr);
    gemm_mfma_kernel<256, 192, 192, 64, 3, true, true, true, false, true, true>
        <<<NGB, 256, 0, stream>>>(t64c, t64a, t64b, wp2, conv2_b, aarr, barr, nullptr, nullptr,
                                  h2b, part, nullptr);
    bn_finalize_kernel<<<256, 256, 0, stream>>>(part, bn2_g, bn2_b, aarr + 256, barr + 256, invN, NGB);

    // ---------- Stage C: 3 bottlenecks ----------
    for (int i = 0; i < 3; ++i) {
        float* aA = aarr + (2 + i * 3) * 256; float* bA = barr + (2 + i * 3) * 256;
        float* aB = aarr + (3 + i * 3) * 256; float* bB = barr + (3 + i * 3) * 256;
        float* aC = aarr + (4 + i * 3) * 256; float* bC = barr + (4 + i * 3) * 256;

        // cheb1: 256->64.
        // i=0: BN2 fused on raw conv2 trunk.
        // i>=1: fused trunk update (stage = BN3_{i-1}(y3b)+base, writeback to h2b).
        if (i == 0)
            gemm_mfma_kernel<64, 256, 256, 256, 1, true, true, true, false, true, true>
                <<<NGB, 256, 0, stream>>>(h2b, nullptr, nullptr, wpc1, bt_c1b,
                                          aarr + 256, barr + 256, nullptr, nullptr,
                                          t64c, part, nullptr);
        else if (i == 1)
            gemm_mfma_kernel<64, 256, 256, 256, 1, true, false, true, false, true, true, true, true, true>
                <<<NGB, 256, 0, stream>>>(y3b, h2b, nullptr, wpc1 + (size_t)1 * 16384, bt_c1b + 64,
                                          aarr + 4 * 256, barr + 4 * 256,     // BN3_0
                                          aarr + 256, barr + 256,             // BN2 (BASEBN)
                                          t64c, part, h2b);
        else
            gemm_mfma_kernel<64, 256, 256, 256, 1, true, false, true, false, true, true, true, false, true>
                <<<NGB, 256, 0, stream>>>(y3b, h2b, nullptr, wpc1 + (size_t)2 * 16384, bt_c1b + 128,
                                          aarr + 7 * 256, barr + 7 * 256,     // BN3_1
                                          nullptr, nullptr,
                                          t64c, part, h2b);
        bn_finalize_kernel<<<64, 256, 0, stream>>>(part, btbn1g + i * 64, btbn1b + i * 64, aA, bA, invN, NGB);

        // cheb2: t64a = L relu(BN(t64c)), t64b = L t64a (folded weights)
        spmm64_kernel<true ><<<NSP64, 256, 0, stream>>>(t64a, t64c, edges, aA, bA);
        spmm64_kernel<false><<<NSP64, 256, 0, stream>>>(t64b, t64a, edges, nullptr, nullptr);
        gemm_mfma_kernel<64, 192, 192, 64, 3, true, true, true, false, true, true>
            <<<NGB, 256, 0, stream>>>(t64c, t64a, t64b, wpc2 + (size_t)i * 12288, bt_c2b + i * 64,
                                      aA, bA, nullptr, nullptr,
                                      t64d, part, nullptr);
        bn_finalize_kernel<<<64, 256, 0, stream>>>(part, btbn2g + i * 64, btbn2b + i * 64, aB, bB, invN, NGB);

        // cheb3: 64->256 (BN2 fused on staging), y3b bf16 out
        gemm_mfma_kernel<256, 64, 64, 64, 1, true, true, true, false, true, true>
            <<<NGB, 256, 0, stream>>>(t64d, nullptr, nullptr, wpc3 + (size_t)i * 16384, bt_c3b + i * 256,
                                      aB, bB, nullptr, nullptr,
                                      y3b, part, nullptr);
        bn_finalize_kernel<<<256, 256, 0, stream>>>(part, btbn3g + i * 256, btbn3b + i * 256, aC, bC, invN, NGB);
    }

    // ---------- Stage D: conv3, folded: z0' = h(W0-W2)+b, z1 = hW1, z2' = 2hW2
    // ee = L z2' + z1; out = L ee + z0'
    float* z0 = scr;
    float* z1 = z0 + (size_t)BV * 8;
    float* z2 = z1 + (size_t)BV * 8;
    float* ee = z2 + (size_t)BV * 8;
    float* aC2 = aarr + 10 * 256;   // i=2 BN3 params
    float* bC2 = barr + 10 * 256;

    gemm_mfma_kernel<32, 256, 256, 256, 1, false, true, true, true, true, false, true>
        <<<NGB, 256, 0, stream>>>(y3b, h2b, nullptr, wp3, bpack,
                                  aC2, bC2, nullptr, nullptr,
                                  z0, nullptr, nullptr);

    spmm8_kernel<2><<<NSP8, 256, 0, stream>>>(ee, z2, z1, edges);
    spmm8_kernel<2><<<NSP8, 256, 0, stream>>>(out, ee, z0, edges);

    (void)in_sizes; (void)n_in; (void)out_size; (void)ws_size;
}

// Round 24
// 290.168 us; speedup vs baseline: 1.3531x; 1.0026x over previous
//
#include <hip/hip_runtime.h>

static constexpr int NBRS = 21;
static constexpr int Nv   = 12288;
static constexpr int BV   = 4 * Nv;            // 49152 rows
static constexpr int NE   = Nv * NBRS;         // 258048 edges
static constexpr float BN_EPS = 1e-5f;

typedef __bf16 bf16x4 __attribute__((ext_vector_type(4)));
typedef __bf16 bf16x8 __attribute__((ext_vector_type(8)));
typedef float  f32x4  __attribute__((ext_vector_type(4)));

__device__ __forceinline__ int xcd_swz(int bid, int grid)
{
    // bijective chunked XCD swizzle (grid % 8 == 0)
    return (bid & 7) * (grid >> 3) + (bid >> 3);
}

// ---------------- SPMM (C=8, fp32, float4: 2 threads/row).
// MODE 0: y = acc; MODE 2: y = acc + x0.
template<int MODE>
__global__ __launch_bounds__(256)
void spmm8_kernel(float* __restrict__ y, const float* __restrict__ x,
                  const float* __restrict__ x0,
                  const int2* __restrict__ edges)
{
    int idx = xcd_swz(blockIdx.x, gridDim.x) * 256 + threadIdx.x;   // over BV*2
    int c4 = idx & 1;
    int row = idx >> 1;
    int v = row % Nv;
    int b = row / Nv;
    int e0 = v * NBRS;
    const float4* x4 = (const float4*)x;
    float4 acc = {0.f, 0.f, 0.f, 0.f};
    #pragma unroll
    for (int j = 0; j < NBRS; ++j) {
        const int2 ed = edges[e0 + j];
        const float a = __int_as_float(ed.x);
        const int u = ed.y;
        float4 xv = x4[(size_t)(b * Nv + u) * 2 + c4];
        acc.x = fmaf(a, xv.x, acc.x);
        acc.y = fmaf(a, xv.y, acc.y);
        acc.z = fmaf(a, xv.z, acc.z);
        acc.w = fmaf(a, xv.w, acc.w);
    }
    if (MODE == 2) {
        float4 p = ((const float4*)x0)[idx];
        acc.x += p.x; acc.y += p.y; acc.z += p.z; acc.w += p.w;
    }
    ((float4*)y)[idx] = acc;
}

// ---------------- SPMM C=64, bf16x8 (16B) per thread, 8 threads/row.
// BNG: apply relu(BN(.)) to gathered elements.
template<bool BNG>
__global__ __launch_bounds__(256)
void spmm64_kernel(__bf16* __restrict__ y, const __bf16* __restrict__ x,
                   const int2* __restrict__ edges,
                   const float* __restrict__ bn_a, const float* __restrict__ bn_b)
{
    int idx = xcd_swz(blockIdx.x, gridDim.x) * 256 + threadIdx.x;   // over BV*8
    int q = idx % 8;
    int v = (idx / 8) % Nv;
    int b = idx / (8 * Nv);
    int e0 = v * NBRS;
    const bf16x8* x8 = (const bf16x8*)x;
    float4 aL, aH, bL, bH;
    if (BNG) {
        aL = ((const float4*)bn_a)[q * 2];     aH = ((const float4*)bn_a)[q * 2 + 1];
        bL = ((const float4*)bn_b)[q * 2];     bH = ((const float4*)bn_b)[q * 2 + 1];
    }
    float acc[8];
    #pragma unroll
    for (int t = 0; t < 8; ++t) acc[t] = 0.f;
    #pragma unroll
    for (int j = 0; j < NBRS; ++j) {
        const int2 ed = edges[e0 + j];
        const float a = __int_as_float(ed.x);
        const int u = ed.y;
        bf16x8 hv = x8[(size_t)(b * Nv + u) * 8 + q];
        float xv[8];
        #pragma unroll
        for (int t = 0; t < 8; ++t) xv[t] = (float)hv[t];
        if (BNG) {
            xv[0] = fmaxf(fmaf(xv[0], aL.x, bL.x), 0.f);
            xv[1] = fmaxf(fmaf(xv[1], aL.y, bL.y), 0.f);
            xv[2] = fmaxf(fmaf(xv[2], aL.z, bL.z), 0.f);
            xv[3] = fmaxf(fmaf(xv[3], aL.w, bL.w), 0.f);
            xv[4] = fmaxf(fmaf(xv[4], aH.x, bH.x), 0.f);
            xv[5] = fmaxf(fmaf(xv[5], aH.y, bH.y), 0.f);
            xv[6] = fmaxf(fmaf(xv[6], aH.z, bH.z), 0.f);
            xv[7] = fmaxf(fmaf(xv[7], aH.w, bH.w), 0.f);
        }
        #pragma unroll
        for (int t = 0; t < 8; ++t) acc[t] = fmaf(a, xv[t], acc[t]);
    }
    bf16x8 o;
    #pragma unroll
    for (int t = 0; t < 8; ++t) o[t] = (__bf16)acc[t];
    ((bf16x8*)y)[idx] = o;
}

// ---------------- unified pack with Chebyshev folding + edge packing.
// Weights: K=3 regions -> (W0 - W2), W1, 2*W2. Edge list: (val, col) interleaved.
__global__ __launch_bounds__(256)
void pack_all_kernel(const float* __restrict__ w1, const float* __restrict__ w2,
                     const float* __restrict__ c1, const float* __restrict__ c2,
                     const float* __restrict__ c3, const float* __restrict__ w3,
                     const float* __restrict__ b3,
                     const float* __restrict__ eval_, const int* __restrict__ col,
                     __bf16* __restrict__ wb, float* __restrict__ bpack,
                     int2* __restrict__ edges)
{
    int t = blockIdx.x * 256 + threadIdx.x;
    if (t >= 194560) {
        int i = t - 194560;
        if (i < 32) { bpack[i] = (i < 8) ? b3[i] : 0.f; return; }
        int e = t - 194592;
        if (e < NE) edges[e] = make_int2(__float_as_int(eval_[e]), col[e]);
        return;
    }
    const float* src; int KSRC, FOUT, FIN, local; bool fold = false, isW3 = false;
    if (t < 2048)        { src = w1;  KSRC = 24;  FOUT = 64;  FIN = 8;  local = t; fold = true; }
    else if (t < 51200)  { src = w2;  KSRC = 192; FOUT = 256; FIN = 64; local = t - 2048; fold = true; }
    else if (t < 100352) { int i = (t - 51200) / 16384;  src = c1 + (size_t)i * 16384;
                           KSRC = 256; FOUT = 64;  FIN = 256; local = (t - 51200) % 16384; }
    else if (t < 137216) { int i = (t - 100352) / 12288; src = c2 + (size_t)i * 12288;
                           KSRC = 192; FOUT = 64;  FIN = 64; local = (t - 100352) % 12288; fold = true; }
    else if (t < 186368) { int i = (t - 137216) / 16384; src = c3 + (size_t)i * 16384;
                           KSRC = 64;  FOUT = 256; FIN = 64; local = (t - 137216) % 16384; }
    else                 { src = w3;  KSRC = 256; FOUT = 32; FIN = 256; local = t - 186368; isW3 = true; }
    const int j    = local & 7;
    const int lane = (local >> 3) & 63;
    const int rest = local >> 9;
    const int NT = FOUT >> 4;
    const int nt = rest % NT;
    const int ks = rest / NT;
    const int k = ks * 32 + (lane >> 4) * 8 + j;
    const int o = nt * 16 + (lane & 15);
    float v = 0.f;
    if (isW3) {
        const int zj = o >> 3, oo = o & 7;
        if (zj == 0)      v = src[(size_t)k * 8 + oo] - src[(size_t)2 * 2048 + k * 8 + oo];
        else if (zj == 1) v = src[(size_t)2048 + k * 8 + oo];
        else if (zj == 2) v = 2.f * src[(size_t)2 * 2048 + k * 8 + oo];
    } else if (k < KSRC) {
        if (fold) {
            if (k < FIN)          v = src[(size_t)k * FOUT + o] - src[(size_t)(k + 2 * FIN) * FOUT + o];
            else if (k < 2 * FIN) v = src[(size_t)k * FOUT + o];
            else                  v = 2.f * src[(size_t)k * FOUT + o];
        } else {
            v = src[(size_t)k * FOUT + o];
        }
    }
    wb[t] = (__bf16)v;
}

// ---------------- MFMA GEMM. INBF: x bf16; OUTBF: write bf16.
// RESID (NSRC=1, INBF): stage = BN(x0) + base(x1) (BASEBN: relu(BN2(base))),
// optionally WRITEBACK the staged value to wbk (trunk update).
template<int FOUT, int KFIN, int KPAD, int FIN, int NSRC,
         bool STATS, bool BN0, bool HAS_BIAS, bool PACKOUT, bool INBF, bool OUTBF,
         bool RESID = false, bool BASEBN = false, bool WRITEBACK = false>
__global__ __launch_bounds__(256)
void gemm_mfma_kernel(const void* __restrict__ x0, const void* __restrict__ x1,
                      const void* __restrict__ x2,
                      const __bf16* __restrict__ wp, const float* __restrict__ bias,
                      const float* __restrict__ bn_a, const float* __restrict__ bn_b,
                      const float* __restrict__ bn_a2, const float* __restrict__ bn_b2,
                      void* __restrict__ out, float2* __restrict__ partial,
                      __bf16* __restrict__ wbk)
{
    constexpr int NT    = FOUT / 16;
    constexpr int NSTEP = KPAD / 32;
    constexpr bool COLS = (NT % 4 == 0);
    constexpr int NT2   = COLS ? NT / 4 : NT;
    constexpr int LDKB  = KPAD + 8;
    constexpr int LDC   = FOUT + 4;
    constexpr size_t XS_B  = (size_t)64 * LDKB * 2;
    constexpr size_t RPK_B = COLS ? (size_t)16 * LDC * 4 : 0;
    constexpr size_t SMEM  = XS_B > RPK_B ? XS_B : RPK_B;
    __shared__ __align__(16) char smem[SMEM];
    __bf16* xs = (__bf16*)smem;

    const int tid = threadIdx.x;
    const int m0 = blockIdx.x * 64;

    constexpr int NF4 = 64 * (KPAD / 4);
    for (int f = tid; f < NF4; f += 256) {
        const int r  = f / (KPAD / 4);
        const int ki = (f % (KPAD / 4)) * 4;
        bf16x4 h;
        if (KFIN == KPAD || ki < KFIN) {
            int i; int kk;
            if constexpr (NSRC == 1) { i = ki; kk = 0; }
            else { kk = ki / FIN; i = ki % FIN; }
            if constexpr (RESID) {
                const __bf16* srcy = (const __bf16*)x0;
                const __bf16* srct = (const __bf16*)x1;
                bf16x4 hy = *(const bf16x4*)(srcy + (size_t)(m0 + r) * FIN + i);
                bf16x4 ht = *(const bf16x4*)(srct + (size_t)(m0 + r) * FIN + i);
                const float4 a4 = *(const float4*)(bn_a + i);
                const float4 b4 = *(const float4*)(bn_b + i);
                float bv0 = (float)ht[0], bv1 = (float)ht[1];
                float bv2 = (float)ht[2], bv3 = (float)ht[3];
                if constexpr (BASEBN) {
                    const float4 p4 = *(const float4*)(bn_a2 + i);
                    const float4 q4 = *(const float4*)(bn_b2 + i);
                    bv0 = fmaxf(fmaf(bv0, p4.x, q4.x), 0.f);
                    bv1 = fmaxf(fmaf(bv1, p4.y, q4.y), 0.f);
                    bv2 = fmaxf(fmaf(bv2, p4.z, q4.z), 0.f);
                    bv3 = fmaxf(fmaf(bv3, p4.w, q4.w), 0.f);
                }
                h[0] = (__bf16)(fmaf((float)hy[0], a4.x, b4.x) + bv0);
                h[1] = (__bf16)(fmaf((float)hy[1], a4.y, b4.y) + bv1);
                h[2] = (__bf16)(fmaf((float)hy[2], a4.z, b4.z) + bv2);
                h[3] = (__bf16)(fmaf((float)hy[3], a4.w, b4.w) + bv3);
                if constexpr (WRITEBACK)
                    *(bf16x4*)(wbk + (size_t)(m0 + r) * FIN + i) = h;
            } else if constexpr (INBF) {
                const __bf16* src = (kk == 0) ? (const __bf16*)x0
                                  : (kk == 1 ? (const __bf16*)x1 : (const __bf16*)x2);
                bf16x4 hv = *(const bf16x4*)(src + (size_t)(m0 + r) * FIN + i);
                if (BN0 && (NSRC == 1 || kk == 0)) {
                    const float4 a4 = *(const float4*)(bn_a + i);
                    const float4 b4 = *(const float4*)(bn_b + i);
                    h[0] = (__bf16)fmaxf(fmaf((float)hv[0], a4.x, b4.x), 0.f);
                    h[1] = (__bf16)fmaxf(fmaf((float)hv[1], a4.y, b4.y), 0.f);
                    h[2] = (__bf16)fmaxf(fmaf((float)hv[2], a4.z, b4.z), 0.f);
                    h[3] = (__bf16)fmaxf(fmaf((float)hv[3], a4.w, b4.w), 0.f);
                } else {
                    h = hv;
                }
            } else {
                const float* src = (kk == 0) ? (const float*)x0
                                 : (kk == 1 ? (const float*)x1 : (const float*)x2);
                float4 v = *(const float4*)(src + (size_t)(m0 + r) * FIN + i);
                if (BN0 && (NSRC == 1 || kk == 0)) {
                    const float4 a4 = *(const float4*)(bn_a + i);
                    const float4 b4 = *(const float4*)(bn_b + i);
                    v.x = fmaxf(fmaf(v.x, a4.x, b4.x), 0.f);
                    v.y = fmaxf(fmaf(v.y, a4.y, b4.y), 0.f);
                    v.z = fmaxf(fmaf(v.z, a4.z, b4.z), 0.f);
                    v.w = fmaxf(fmaf(v.w, a4.w, b4.w), 0.f);
                }
                h[0] = (__bf16)v.x; h[1] = (__bf16)v.y; h[2] = (__bf16)v.z; h[3] = (__bf16)v.w;
            }
        } else {
            h[0] = (__bf16)0.f; h[1] = (__bf16)0.f; h[2] = (__bf16)0.f; h[3] = (__bf16)0.f;
        }
        *(bf16x4*)(xs + (size_t)r * LDKB + ki) = h;
    }
    __syncthreads();

    const int lane = tid & 63;
    const int wv   = tid >> 6;
    const int lo   = lane & 15;
    const int hi   = lane >> 4;

    if constexpr (COLS) {
        f32x4 acc[4][NT2];
        #pragma unroll
        for (int mr = 0; mr < 4; ++mr)
            #pragma unroll
            for (int n = 0; n < NT2; ++n) acc[mr][n] = (f32x4){0.f, 0.f, 0.f, 0.f};

        #pragma unroll
        for (int ks = 0; ks < NSTEP; ++ks) {
            bf16x8 bfr[NT2];
            #pragma unroll
            for (int n = 0; n < NT2; ++n)
                bfr[n] = *(const bf16x8*)(wp + ((size_t)(ks * NT + wv * NT2 + n) * 64 + lane) * 8);
            bf16x8 afr[4];
            #pragma unroll
            for (int mr = 0; mr < 4; ++mr)
                afr[mr] = *(const bf16x8*)(xs + (size_t)(mr * 16 + lo) * LDKB + ks * 32 + hi * 8);
            #pragma unroll
            for (int n = 0; n < NT2; ++n)
                #pragma unroll
                for (int mr = 0; mr < 4; ++mr)
                    acc[mr][n] = __builtin_amdgcn_mfma_f32_16x16x32_bf16(afr[mr], bfr[n], acc[mr][n], 0, 0, 0);
        }

        #pragma unroll
        for (int n = 0; n < NT2; ++n) {
            const int o = wv * (FOUT / 4) + n * 16 + lo;
            const float bo = HAS_BIAS ? bias[o] : 0.f;
            #pragma unroll
            for (int mr = 0; mr < 4; ++mr)
                #pragma unroll
                for (int j = 0; j < 4; ++j) acc[mr][n][j] += bo;
        }

        if constexpr (STATS) {
            #pragma unroll
            for (int n = 0; n < NT2; ++n) {
                float s = 0.f, q = 0.f;
                #pragma unroll
                for (int mr = 0; mr < 4; ++mr)
                    #pragma unroll
                    for (int j = 0; j < 4; ++j) {
                        const float v = acc[mr][n][j];
                        s += v; q = fmaf(v, v, q);
                    }
                s += __shfl_xor(s, 16); q += __shfl_xor(q, 16);
                s += __shfl_xor(s, 32); q += __shfl_xor(q, 32);
                if (lane < 16) {
                    const int o = wv * (FOUT / 4) + n * 16 + lo;
                    partial[(size_t)o * gridDim.x + blockIdx.x] = make_float2(s, q);
                }
            }
        }

        float* cs = (float*)smem;
        #pragma unroll
        for (int mr = 0; mr < 4; ++mr) {
            __syncthreads();
            #pragma unroll
            for (int n = 0; n < NT2; ++n) {
                const int o = wv * (FOUT / 4) + n * 16 + lo;
                #pragma unroll
                for (int j = 0; j < 4; ++j)
                    cs[(size_t)(hi * 4 + j) * LDC + o] = acc[mr][n][j];
            }
            __syncthreads();
            for (int t = tid; t < 16 * (FOUT / 4); t += 256) {
                const int rr = t / (FOUT / 4);
                const int c4 = (t % (FOUT / 4)) * 4;
                const float4 v = *(const float4*)(cs + (size_t)rr * LDC + c4);
                if constexpr (OUTBF) {
                    bf16x4 hv;
                    hv[0] = (__bf16)v.x; hv[1] = (__bf16)v.y;
                    hv[2] = (__bf16)v.z; hv[3] = (__bf16)v.w;
                    *(bf16x4*)((__bf16*)out + (size_t)(m0 + mr * 16 + rr) * FOUT + c4) = hv;
                } else {
                    *(float4*)((float*)out + (size_t)(m0 + mr * 16 + rr) * FOUT + c4) = v;
                }
            }
        }
    } else {
        f32x4 acc[NT];
        #pragma unroll
        for (int nt = 0; nt < NT; ++nt) acc[nt] = (f32x4){0.f, 0.f, 0.f, 0.f};
        const int arow = wv * 16 + lo;
        #pragma unroll
        for (int ks = 0; ks < NSTEP; ++ks) {
            const bf16x8 a = *(const bf16x8*)(xs + (size_t)arow * LDKB + ks * 32 + hi * 8);
            #pragma unroll
            for (int nt = 0; nt < NT; ++nt) {
                const bf16x8 b = *(const bf16x8*)(wp + ((size_t)(ks * NT + nt) * 64 + lane) * 8);
                acc[nt] = __builtin_amdgcn_mfma_f32_16x16x32_bf16(a, b, acc[nt], 0, 0, 0);
            }
        }
        #pragma unroll
        for (int nt = 0; nt < NT; ++nt) {
            const int o = nt * 16 + lo;
            const float bo = HAS_BIAS ? bias[o] : 0.f;
            #pragma unroll
            for (int j = 0; j < 4; ++j) {
                const float v = acc[nt][j] + bo;
                const int m = m0 + wv * 16 + hi * 4 + j;
                if constexpr (PACKOUT) {
                    const int zj = o >> 3;
                    if (zj < 3) ((float*)out)[((size_t)zj * BV + m) * 8 + (o & 7)] = v;
                } else {
                    ((float*)out)[(size_t)m * FOUT + o] = v;
                }
            }
        }
    }
}

// ---------------- BN finalize: one block per channel, coalesced over [C][nblk]
__global__ __launch_bounds__(256)
void bn_finalize_kernel(const float2* __restrict__ partial,
                        const float* __restrict__ g, const float* __restrict__ b,
                        float* __restrict__ a_out, float* __restrict__ b_out,
                        float invN, int nblk)
{
    __shared__ float2 red[4];
    const int c = blockIdx.x;
    const float2* p = partial + (size_t)c * nblk;
    float s = 0.f, ss = 0.f;
    for (int k = threadIdx.x; k < nblk; k += 256) {
        const float2 v = p[k];
        s += v.x; ss += v.y;
    }
    #pragma unroll
    for (int off = 32; off > 0; off >>= 1) {
        s  += __shfl_down(s, off);
        ss += __shfl_down(ss, off);
    }
    if ((threadIdx.x & 63) == 0) red[threadIdx.x >> 6] = make_float2(s, ss);
    __syncthreads();
    if (threadIdx.x == 0) {
        float ts = 0.f, tq = 0.f;
        #pragma unroll
        for (int i = 0; i < 4; ++i) { ts += red[i].x; tq += red[i].y; }
        const float m = ts * invN;
        const float var = tq * invN - m * m;
        const float a = g[c] * rsqrtf(var + BN_EPS);
        a_out[c] = a;
        b_out[c] = b[c] - m * a;
    }
}

extern "C" void kernel_launch(void* const* d_in, const int* in_sizes, int n_in,
                              void* d_out, int out_size, void* d_ws, size_t ws_size,
                              hipStream_t stream)
{
    const float* x       = (const float*)d_in[0];
    const int*   col     = (const int*)  d_in[2];
    const float* eval_   = (const float*)d_in[3];
    const float* conv1_w = (const float*)d_in[4];
    const float* conv1_b = (const float*)d_in[5];
    const float* bn1_g   = (const float*)d_in[6];
    const float* bn1_b   = (const float*)d_in[7];
    const float* conv2_w = (const float*)d_in[8];
    const float* conv2_b = (const float*)d_in[9];
    const float* bn2_g   = (const float*)d_in[10];
    const float* bn2_b   = (const float*)d_in[11];
    const float* bt_c1w  = (const float*)d_in[12];
    const float* bt_c1b  = (const float*)d_in[13];
    const float* bt_c2w  = (const float*)d_in[14];
    const float* bt_c2b  = (const float*)d_in[15];
    const float* bt_c3w  = (const float*)d_in[16];
    const float* bt_c3b  = (const float*)d_in[17];
    const float* btbn1g  = (const float*)d_in[18];
    const float* btbn1b  = (const float*)d_in[19];
    const float* btbn2g  = (const float*)d_in[20];
    const float* btbn2b  = (const float*)d_in[21];
    const float* btbn3g  = (const float*)d_in[22];
    const float* btbn3b  = (const float*)d_in[23];
    const float* conv3_w = (const float*)d_in[24];
    const float* conv3_b = (const float*)d_in[25];
    float* out = (float*)d_out;

    __bf16* h2b  = (__bf16*)d_ws;                  // BV*256 bf16 (trunk)
    __bf16* y3b  = h2b + (size_t)BV * 256;         // BV*256 bf16 (cheb3 out)
    __bf16* t64a = y3b + (size_t)BV * 256;         // 4 x BV*64 bf16
    __bf16* t64b = t64a + (size_t)BV * 64;
    __bf16* t64c = t64b + (size_t)BV * 64;
    __bf16* t64d = t64c + (size_t)BV * 64;
    float*  scr  = (float*)(t64d + (size_t)BV * 64);   // BV*32 fp32
    float*  aarr = scr + (size_t)BV * 32;          // 11*256
    float*  barr = aarr + 11 * 256;                // 11*256
    float*  bpack = barr + 11 * 256;               // 32
    __bf16* wb   = (__bf16*)(bpack + 32);          // bf16 weight arena
    __bf16* wp1  = wb;                             // 2048
    __bf16* wp2  = wp1 + 2048;                     // 49152
    __bf16* wpc1 = wp2 + 49152;                    // 49152
    __bf16* wpc2 = wpc1 + 49152;                   // 36864
    __bf16* wpc3 = wpc2 + 36864;                   // 49152
    __bf16* wp3  = wpc3 + 49152;                   // 8192
    float2* part = (float2*)(wp3 + 8192);          // 256 * 768
    int2*   edges = (int2*)(part + 256 * 768);     // NE (2 MB)

    float* t8a = scr;                              // BV*8 (stage A)
    float* t8b = scr + (size_t)BV * 8;

    const float invN = 1.f / (float)BV;
    const int NGB  = BV / 64;                      // 768
    const int NSP64 = BV * 8 / 256;                // 1536
    const int NSP8  = BV * 2 / 256;                // 384

    // ---------- packing: 1 launch (cheb-folded weights + edge list) ----------
    pack_all_kernel<<<1769, 256, 0, stream>>>(conv1_w, conv2_w, bt_c1w, bt_c2w, bt_c3w,
                                              conv3_w, conv3_b, eval_, col, wb, bpack, edges);

    // ---------- Stage A: conv1 (8 -> 64), folded: t8a = Lx, t8b = L t8a ----------
    spmm8_kernel<0><<<NSP8, 256, 0, stream>>>(t8a, x, nullptr, edges);
    spmm8_kernel<0><<<NSP8, 256, 0, stream>>>(t8b, t8a, nullptr, edges);
    gemm_mfma_kernel<64, 24, 32, 8, 3, true, false, true, false, false, true>
        <<<NGB, 256, 0, stream>>>(x, t8a, t8b, wp1, conv1_b, nullptr, nullptr, nullptr, nullptr,
                                  t64c, part, nullptr);
    bn_finalize_kernel<<<64, 256, 0, stream>>>(part, bn1_g, bn1_b, aarr, barr, invN, NGB);

    // ---------- Stage B: conv2 (64 -> 256); t64a = L h, t64b = L t64a ----------
    spmm64_kernel<true ><<<NSP64, 256, 0, stream>>>(t64a, t64c, edges, aarr, barr);
    spmm64_kernel<false><<<NSP64, 256, 0, stream>>>(t64b, t64a, edges, nullptr, nullptr);
    gemm_mfma_kernel<256, 192, 192, 64, 3, true, true, true, false, true, true>
        <<<NGB, 256, 0, stream>>>(t64c, t64a, t64b, wp2, conv2_b, aarr, barr, nullptr, nullptr,
                                  h2b, part, nullptr);
    bn_finalize_kernel<<<256, 256, 0, stream>>>(part, bn2_g, bn2_b, aarr + 256, barr + 256, invN, NGB);

    // ---------- Stage C: 3 bottlenecks ----------
    for (int i = 0; i < 3; ++i) {
        float* aA = aarr + (2 + i * 3) * 256; float* bA = barr + (2 + i * 3) * 256;
        float* aB = aarr + (3 + i * 3) * 256; float* bB = barr + (3 + i * 3) * 256;
        float* aC = aarr + (4 + i * 3) * 256; float* bC = barr + (4 + i * 3) * 256;

        // cheb1: 256->64.
        // i=0: BN2 fused on raw conv2 trunk.
        // i>=1: fused trunk update (stage = BN3_{i-1}(y3b)+base, writeback to h2b).
        if (i == 0)
            gemm_mfma_kernel<64, 256, 256, 256, 1, true, true, true, false, true, true>
                <<<NGB, 256, 0, stream>>>(h2b, nullptr, nullptr, wpc1, bt_c1b,
                                          aarr + 256, barr + 256, nullptr, nullptr,
                                          t64c, part, nullptr);
        else if (i == 1)
            gemm_mfma_kernel<64, 256, 256, 256, 1, true, false, true, false, true, true, true, true, true>
                <<<NGB, 256, 0, stream>>>(y3b, h2b, nullptr, wpc1 + (size_t)1 * 16384, bt_c1b + 64,
                                          aarr + 4 * 256, barr + 4 * 256,     // BN3_0
                                          aarr + 256, barr + 256,             // BN2 (BASEBN)
                                          t64c, part, h2b);
        else
            gemm_mfma_kernel<64, 256, 256, 256, 1, true, false, true, false, true, true, true, false, true>
                <<<NGB, 256, 0, stream>>>(y3b, h2b, nullptr, wpc1 + (size_t)2 * 16384, bt_c1b + 128,
                                          aarr + 7 * 256, barr + 7 * 256,     // BN3_1
                                          nullptr, nullptr,
                                          t64c, part, h2b);
        bn_finalize_kernel<<<64, 256, 0, stream>>>(part, btbn1g + i * 64, btbn1b + i * 64, aA, bA, invN, NGB);

        // cheb2: t64a = L relu(BN(t64c)), t64b = L t64a (folded weights)
        spmm64_kernel<true ><<<NSP64, 256, 0, stream>>>(t64a, t64c, edges, aA, bA);
        spmm64_kernel<false><<<NSP64, 256, 0, stream>>>(t64b, t64a, edges, nullptr, nullptr);
        gemm_mfma_kernel<64, 192, 192, 64, 3, true, true, true, false, true, true>
            <<<NGB, 256, 0, stream>>>(t64c, t64a, t64b, wpc2 + (size_t)i * 12288, bt_c2b + i * 64,
                                      aA, bA, nullptr, nullptr,
                                      t64d, part, nullptr);
        bn_finalize_kernel<<<64, 256, 0, stream>>>(part, btbn2g + i * 64, btbn2b + i * 64, aB, bB, invN, NGB);

        // cheb3: 64->256 (BN2 fused on staging), y3b bf16 out
        gemm_mfma_kernel<256, 64, 64, 64, 1, true, true, true, false, true, true>
            <<<NGB, 256, 0, stream>>>(t64d, nullptr, nullptr, wpc3 + (size_t)i * 16384, bt_c3b + i * 256,
                                      aB, bB, nullptr, nullptr,
                                      y3b, part, nullptr);
        bn_finalize_kernel<<<256, 256, 0, stream>>>(part, btbn3g + i * 256, btbn3b + i * 256, aC, bC, invN, NGB);
    }

    // ---------- Stage D: conv3, folded: z0' = h(W0-W2)+b, z1 = hW1, z2' = 2hW2
    // ee = L z2' + z1; out = L ee + z0'
    float* z0 = scr;
    float* z1 = z0 + (size_t)BV * 8;
    float* z2 = z1 + (size_t)BV * 8;
    float* ee = z2 + (size_t)BV * 8;
    float* aC2 = aarr + 10 * 256;   // i=2 BN3 params
    float* bC2 = barr + 10 * 256;

    gemm_mfma_kernel<32, 256, 256, 256, 1, false, true, true, true, true, false, true>
        <<<NGB, 256, 0, stream>>>(y3b, h2b, nullptr, wp3, bpack,
                                  aC2, bC2, nullptr, nullptr,
                                  z0, nullptr, nullptr);

    spmm8_kernel<2><<<NSP8, 256, 0, stream>>>(ee, z2, z1, edges);
    spmm8_kernel<2><<<NSP8, 256, 0, stream>>>(out, ee, z0, edges);

    (void)in_sizes; (void)n_in; (void)out_size; (void)ws_size;
}